// Round 4
// baseline (517.327 us; speedup 1.0000x reference)
//
#include <hip/hip_runtime.h>

// Problem constants (fixed shapes from setup_inputs)
#define HH 540
#define WW 960
#define NC 3
#define ND 60          // disparities 1..60
#define NP (HH * WW)   // 518400 pixels per plane
#define STRIP 45       // rows per block in cost kernel (540 = 12*45)
#define OUTC 248       // output columns per col-block (4 blocks * 248 >= 960)
#define DT 6           // disparities per block (60 = 10 * 6)
#define NDT (ND / DT)  // 10 disparity tiles
#define RBW 264        // staged R row width (covers 261 needed cols)
#define VBW 260        // vbuf row stride (multiple of 4 -> 16B-aligned b128 reads)
#define GRP 31         // 8-col groups per disparity in phase 2 (248/8)
#define P2T (DT * GRP) // 186 phase-2 threads

// ---------------------------------------------------------------------------
// Kernel 1: channel-summed horizontal 9-window sums (zero padding on x)
// ---------------------------------------------------------------------------
__global__ __launch_bounds__(256) void k_stats_h(
    const float* __restrict__ L, const float* __restrict__ R,
    float* __restrict__ hsL, float* __restrict__ hsLL,
    float* __restrict__ hsR, float* __restrict__ hsRR) {
    int x = blockIdx.x * blockDim.x + threadIdx.x;
    int y = blockIdx.y;
    if (x >= WW) return;
    float a = 0.f, a2 = 0.f, b = 0.f, b2 = 0.f;
#pragma unroll
    for (int dx = -4; dx <= 4; ++dx) {
        int xx = x + dx;
        if (xx < 0 || xx >= WW) continue;
#pragma unroll
        for (int c = 0; c < NC; ++c) {
            float l = L[(c * HH + y) * WW + xx];
            float r = R[(c * HH + y) * WW + xx];
            a += l; a2 = fmaf(l, l, a2);
            b += r; b2 = fmaf(r, r, b2);
        }
    }
    int o = y * WW + x;
    hsL[o] = a; hsLL[o] = a2; hsR[o] = b; hsRR[o] = b2;
}

// ---------------------------------------------------------------------------
// Kernel 2: vertical 9-window sums + finalize stats
// ---------------------------------------------------------------------------
__global__ __launch_bounds__(256) void k_stats_v(
    const float* __restrict__ hsL, const float* __restrict__ hsLL,
    const float* __restrict__ hsR, const float* __restrict__ hsRR,
    float* __restrict__ LSum, float* __restrict__ sqLa,
    float* __restrict__ RSn, float* __restrict__ sqRa) {
    int x = blockIdx.x * blockDim.x + threadIdx.x;
    int y = blockIdx.y;
    if (x >= WW) return;
    float a = 0.f, a2 = 0.f, b = 0.f, b2 = 0.f;
#pragma unroll
    for (int dy = -4; dy <= 4; ++dy) {
        int yy = y + dy;
        if (yy < 0 || yy >= HH) continue;
        int o = yy * WW + x;
        a += hsL[o]; a2 += hsLL[o]; b += hsR[o]; b2 += hsRR[o];
    }
    const float inv_n = 1.0f / 243.0f;
    int o = y * WW + x;
    LSum[o] = a;
    sqLa[o] = sqrtf(fmaf(-a * inv_n, a, a2) + 1e-5f);
    RSn[o]  = b * inv_n;
    sqRa[o] = sqrtf(fmaf(-b * inv_n, b, b2) + 1e-5f);
}

// ---------------------------------------------------------------------------
// Kernel 3: d-tiled cost kernel.
// Grid: (4 col-blocks, 12 row-strips, 10 d-tiles). 256 threads.
// Phase 1: thread t owns q-column xq = x0-4+t; 6 vertical sliding sums v[k]
//          (one per disparity in tile), Q read from LDS-staged R rows.
// Phase 2: 186 threads each own one (d, 8-col group); horizontal 9-sum via
//          4x ds_read_b128 + register sliding; writes costL and costR.
// ---------------------------------------------------------------------------
__global__ __launch_bounds__(256) void k_cost(
    const float* __restrict__ L, const float* __restrict__ R,
    const float* __restrict__ LSum, const float* __restrict__ sqLa,
    const float* __restrict__ RSn, const float* __restrict__ sqRa,
    float* __restrict__ out) {
    __shared__ __align__(16) float rb[2][NC][RBW];
    __shared__ __align__(16) float vbuf[DT * VBW];

    const int t   = threadIdx.x;
    const int y0  = blockIdx.y * STRIP;
    const int x0  = blockIdx.x * OUTC;
    const int dlo = blockIdx.z * DT + 1;        // lowest disparity in tile
    const int xq  = x0 - 4 + t;                 // this thread's q-column
    const int rbase = x0 - dlo - 9;             // global col of rb[.][.][0]
    const bool xok = ((unsigned)xq < WW);

    float v[DT];
#pragma unroll
    for (int k = 0; k < DT; ++k) v[k] = 0.f;

    // ---- phase-2 thread mapping (fixed per thread) ----
    const int d_k = (t < P2T) ? (t / GRP) : (DT - 1);
    const int g   = t - ((t < P2T) ? d_k * GRP : t);  // valid only for t<P2T
    const bool p2 = (t < P2T);
    const int X   = x0 + 8 * ((t < P2T) ? (t - d_k * GRP) : 0);
    const int d   = dlo + d_k;
    float* const outLp = out + (size_t)(d - 1) * NP;
    float* const outRp = outLp + (size_t)ND * NP;
    (void)g;

    // ---- staging helpers ----
    auto stageR = [&](int slot, int row) {
#pragma unroll
        for (int ch = 0; ch < NC; ++ch) {
            int gc = rbase + t;
            gc = max(0, min(WW - 1, gc));
            rb[slot][ch][t] = R[(ch * HH + row) * WW + gc];
            if (t < RBW - 256) {
                int gc2 = rbase + t + 256;
                gc2 = max(0, min(WW - 1, gc2));
                rb[slot][ch][t + 256] = R[(ch * HH + row) * WW + gc2];
            }
        }
    };
    auto loadL = [&](int row, float* l) {
#pragma unroll
        for (int ch = 0; ch < NC; ++ch)
            l[ch] = xok ? L[(ch * HH + row) * WW + xq] : 0.f;
    };

    // ---- prologue: build v over rows [y0-4, y0+4] ----
    for (int r = y0 - 4; r <= y0 + 4; ++r) {
        const bool rv = ((unsigned)r < HH);
        float l[NC] = {0.f, 0.f, 0.f};
        if (rv) { stageR(0, r); loadL(r, l); }
        __syncthreads();
        if (rv && xok) {
#pragma unroll
            for (int k = 0; k < DT; ++k) {
                if (xq >= dlo + k) {
                    const int ri = t + 5 - k;
                    float q = l[0] * rb[0][0][ri];
                    q = fmaf(l[1], rb[0][1][ri], q);
                    q = fmaf(l[2], rb[0][2][ri], q);
                    v[k] += q;
                }
            }
        }
        __syncthreads();
    }

    // ---- main loop over output rows ----
    for (int y = y0; y < y0 + STRIP; ++y) {
        const int rA = y + 5, rS = y - 4;
        const bool vA = ((unsigned)rA < HH), vS = ((unsigned)rS < HH);
        float lA[NC] = {0.f, 0.f, 0.f}, lS[NC] = {0.f, 0.f, 0.f};
        if (vA) { stageR(0, rA); loadL(rA, lA); }
        if (vS) { stageR(1, rS); loadL(rS, lS); }
#pragma unroll
        for (int k = 0; k < DT; ++k) vbuf[k * VBW + t] = v[k];
        __syncthreads();

        // ---- phase 2: outputs for row y ----
        if (p2 && X < WW) {
            const float4* vb = (const float4*)&vbuf[d_k * VBW + (X - x0)];
            float4 w0 = vb[0], w1 = vb[1], w2 = vb[2], w3 = vb[3];
            const float q0 = w0.x, q1 = w0.y, q2 = w0.z, q3 = w0.w;
            const float q4 = w1.x, q5 = w1.y, q6 = w1.z, q7 = w1.w;
            const float q8 = w2.x, q9 = w2.y, q10 = w2.z, q11 = w2.w;
            const float q12 = w3.x, q13 = w3.y, q14 = w3.z, q15 = w3.w;
            float s[8];
            s[0] = ((q0 + q1) + (q2 + q3)) + ((q4 + q5) + (q6 + q7)) + q8;
            s[1] = s[0] + q9  - q0;
            s[2] = s[1] + q10 - q1;
            s[3] = s[2] + q11 - q2;
            s[4] = s[3] + q12 - q3;
            s[5] = s[4] + q13 - q4;
            s[6] = s[5] + q14 - q5;
            s[7] = s[6] + q15 - q6;

            const int o = y * WW + X;
            float4 lsA = *(const float4*)&LSum[o];
            float4 lsB = *(const float4*)&LSum[o + 4];
            float4 slA = *(const float4*)&sqLa[o];
            float4 slB = *(const float4*)&sqLa[o + 4];
            const float ls[8] = {lsA.x, lsA.y, lsA.z, lsA.w, lsB.x, lsB.y, lsB.z, lsB.w};
            const float sl[8] = {slA.x, slA.y, slA.z, slA.w, slB.x, slB.y, slB.z, slB.w};

            if (X >= d && (X + 7) < (WW - d)) {
                // fast interior path: all 8 cols valid, no zero regions
                float cl[8];
#pragma unroll
                for (int j = 0; j < 8; ++j) {
                    const int od = o + j - d;
                    float num = fmaf(-ls[j], RSn[od], s[j]) + 1e-6f;
                    float den = fmaf(sl[j], sqRa[od], 1e-6f);
                    cl[j] = num * __builtin_amdgcn_rcpf(den);
                    outRp[od] = cl[j];
                }
                *(float4*)&outLp[o]     = make_float4(cl[0], cl[1], cl[2], cl[3]);
                *(float4*)&outLp[o + 4] = make_float4(cl[4], cl[5], cl[6], cl[7]);
            } else {
#pragma unroll
                for (int j = 0; j < 8; ++j) {
                    const int x = X + j;
                    float cl = 0.f;
                    if (x >= d) {
                        const int od = o + j - d;
                        float num = fmaf(-ls[j], RSn[od], s[j]) + 1e-6f;
                        float den = fmaf(sl[j], sqRa[od], 1e-6f);
                        cl = num * __builtin_amdgcn_rcpf(den);
                        outRp[od] = cl;
                    }
                    outLp[o + j] = cl;
                    if (x >= WW - d) outRp[o + j] = 0.f;
                }
            }
        }

        // ---- slide vertical sums: rows [y-4,y+4] -> [y-3,y+5] ----
        if (xok) {
#pragma unroll
            for (int k = 0; k < DT; ++k) {
                const int ri = t + 5 - k;
                const bool qv = (xq >= dlo + k);
                float qa = 0.f, qs = 0.f;
                if (vA && qv) {
                    qa = lA[0] * rb[0][0][ri];
                    qa = fmaf(lA[1], rb[0][1][ri], qa);
                    qa = fmaf(lA[2], rb[0][2][ri], qa);
                }
                if (vS && qv) {
                    qs = lS[0] * rb[1][0][ri];
                    qs = fmaf(lS[1], rb[1][1][ri], qs);
                    qs = fmaf(lS[2], rb[1][2][ri], qs);
                }
                v[k] += qa - qs;
            }
        }
        __syncthreads();
    }
}

// ---------------------------------------------------------------------------
extern "C" void kernel_launch(void* const* d_in, const int* in_sizes, int n_in,
                              void* d_out, int out_size, void* d_ws, size_t ws_size,
                              hipStream_t stream) {
    const float* L = (const float*)d_in[0];
    const float* R = (const float*)d_in[1];
    float* out = (float*)d_out;
    float* ws = (float*)d_ws;

    float* hsL  = ws + 0 * (size_t)NP;
    float* hsLL = ws + 1 * (size_t)NP;
    float* hsR  = ws + 2 * (size_t)NP;
    float* hsRR = ws + 3 * (size_t)NP;
    float* LSum = ws + 4 * (size_t)NP;
    float* sqLa = ws + 5 * (size_t)NP;
    float* RSn  = ws + 6 * (size_t)NP;
    float* sqRa = ws + 7 * (size_t)NP;

    dim3 blk(256);
    dim3 g1((WW + 255) / 256, HH);
    k_stats_h<<<g1, blk, 0, stream>>>(L, R, hsL, hsLL, hsR, hsRR);
    k_stats_v<<<g1, blk, 0, stream>>>(hsL, hsLL, hsR, hsRR, LSum, sqLa, RSn, sqRa);

    dim3 g3((WW + OUTC - 1) / OUTC, HH / STRIP, NDT);
    k_cost<<<g3, blk, 0, stream>>>(L, R, LSum, sqLa, RSn, sqRa, out);
}

// Round 5
// 409.533 us; speedup vs baseline: 1.2632x; 1.2632x over previous
//
#include <hip/hip_runtime.h>

// Problem constants (fixed shapes from setup_inputs)
#define HH 540
#define WW 960
#define NC 3
#define ND 60          // disparities 1..60
#define NP (HH * WW)   // 518400 pixels per plane
#define STRIP 15       // rows per block (540 = 36*15) -> 1440 blocks = 5.6/CU
#define OUTC 248       // output columns per col-block
#define DT 6           // disparities per block (60 = 10 * 6)
#define NDT (ND / DT)  // 10 disparity tiles
#define RBW 264        // staged R row width
#define VBW 260        // vbuf row stride (multiple of 4 -> 16B-aligned b128)
#define GRP 31         // 8-col groups per disparity in phase 2 (248/8)
#define P2T (DT * GRP) // 186 phase-2 threads

// ---------------------------------------------------------------------------
// Kernel 1: channel-summed horizontal 9-window sums (zero padding on x)
// ---------------------------------------------------------------------------
__global__ __launch_bounds__(256) void k_stats_h(
    const float* __restrict__ L, const float* __restrict__ R,
    float* __restrict__ hsL, float* __restrict__ hsLL,
    float* __restrict__ hsR, float* __restrict__ hsRR) {
    int x = blockIdx.x * blockDim.x + threadIdx.x;
    int y = blockIdx.y;
    if (x >= WW) return;
    float a = 0.f, a2 = 0.f, b = 0.f, b2 = 0.f;
#pragma unroll
    for (int dx = -4; dx <= 4; ++dx) {
        int xx = x + dx;
        if (xx < 0 || xx >= WW) continue;
#pragma unroll
        for (int c = 0; c < NC; ++c) {
            float l = L[(c * HH + y) * WW + xx];
            float r = R[(c * HH + y) * WW + xx];
            a += l; a2 = fmaf(l, l, a2);
            b += r; b2 = fmaf(r, r, b2);
        }
    }
    int o = y * WW + x;
    hsL[o] = a; hsLL[o] = a2; hsR[o] = b; hsRR[o] = b2;
}

// ---------------------------------------------------------------------------
// Kernel 2: vertical 9-window sums + finalize stats
// ---------------------------------------------------------------------------
__global__ __launch_bounds__(256) void k_stats_v(
    const float* __restrict__ hsL, const float* __restrict__ hsLL,
    const float* __restrict__ hsR, const float* __restrict__ hsRR,
    float* __restrict__ LSum, float* __restrict__ sqLa,
    float* __restrict__ RSn, float* __restrict__ sqRa) {
    int x = blockIdx.x * blockDim.x + threadIdx.x;
    int y = blockIdx.y;
    if (x >= WW) return;
    float a = 0.f, a2 = 0.f, b = 0.f, b2 = 0.f;
#pragma unroll
    for (int dy = -4; dy <= 4; ++dy) {
        int yy = y + dy;
        if (yy < 0 || yy >= HH) continue;
        int o = yy * WW + x;
        a += hsL[o]; a2 += hsLL[o]; b += hsR[o]; b2 += hsRR[o];
    }
    const float inv_n = 1.0f / 243.0f;
    int o = y * WW + x;
    LSum[o] = a;
    sqLa[o] = sqrtf(fmaf(-a * inv_n, a, a2) + 1e-5f);
    RSn[o]  = b * inv_n;
    sqRa[o] = sqrtf(fmaf(-b * inv_n, b, b2) + 1e-5f);
}

// ---------------------------------------------------------------------------
// Kernel 3: d-tiled cost kernel, single-sync parity double-buffered.
// Grid: (4 col-blocks, 36 row-strips, 10 d-tiles) = 1440 blocks, 256 thr.
// Phase 1: thread t owns q-column xq = x0-4+t; 6 vertical sliding sums v[k];
//          R rows staged in LDS (parity dbuf), L in registers.
// Phase 2: 186 threads each own one (d, 8-col group); horizontal 9-sum via
//          4x ds_read_b128 of vbuf[parity] + register sliding sum.
// Exactly ONE __syncthreads per row: writes go to slot (it&1); reads of a
// slot finish before the NEXT sync, and the next write to the same parity
// happens after that sync -> race-free.
// ---------------------------------------------------------------------------
__global__ __launch_bounds__(256) void k_cost(
    const float* __restrict__ L, const float* __restrict__ R,
    const float* __restrict__ LSum, const float* __restrict__ sqLa,
    const float* __restrict__ RSn, const float* __restrict__ sqRa,
    float* __restrict__ out) {
    __shared__ __align__(16) float rbA[2][NC][RBW];
    __shared__ __align__(16) float rbS[2][NC][RBW];
    __shared__ __align__(16) float vbuf[2][DT][VBW];

    const int t   = threadIdx.x;
    const int y0  = blockIdx.y * STRIP;
    const int x0  = blockIdx.x * OUTC;
    const int dlo = blockIdx.z * DT + 1;        // lowest disparity in tile
    const int xq  = x0 - 4 + t;                 // this thread's q-column
    const int rbase = x0 - dlo - 9;             // global col of rb[.][0]
    const bool xok = ((unsigned)xq < WW);

    float v[DT];
#pragma unroll
    for (int k = 0; k < DT; ++k) v[k] = 0.f;

    // ---- phase-2 thread mapping (fixed per thread) ----
    const bool p2 = (t < P2T);
    const int d_k = p2 ? (t / GRP) : 0;
    const int X   = x0 + 8 * (p2 ? (t - d_k * GRP) : 0);
    const int d   = dlo + d_k;
    float* const outLp = out + (size_t)(d - 1) * NP;
    float* const outRp = outLp + (size_t)ND * NP;

    // ---- helpers ----
    auto stage = [&](float (*dst)[RBW], int row) {
#pragma unroll
        for (int ch = 0; ch < NC; ++ch) {
            int gc = max(0, min(WW - 1, rbase + t));
            dst[ch][t] = R[(ch * HH + row) * WW + gc];
            if (t < RBW - 256) {
                int gc2 = max(0, min(WW - 1, rbase + t + 256));
                dst[ch][t + 256] = R[(ch * HH + row) * WW + gc2];
            }
        }
    };
    auto loadL = [&](int row, float* l) {
#pragma unroll
        for (int ch = 0; ch < NC; ++ch)
            l[ch] = xok ? L[(ch * HH + row) * WW + xq] : 0.f;
    };

    // ---- prologue: build v over rows [y0-4, y0+4]; one sync per row ----
    for (int p = 0; p < 9; ++p) {
        const int r = y0 - 4 + p;
        const bool rv = ((unsigned)r < HH);
        const int s = p & 1;
        float l[NC] = {0.f, 0.f, 0.f};
        if (rv) { stage(rbA[s], r); loadL(r, l); }
        __syncthreads();
        if (rv && xok) {
#pragma unroll
            for (int k = 0; k < DT; ++k) {
                if (xq >= dlo + k) {
                    const int ri = t + 5 - k;
                    float q = l[0] * rbA[s][0][ri];
                    q = fmaf(l[1], rbA[s][1][ri], q);
                    q = fmaf(l[2], rbA[s][2][ri], q);
                    v[k] += q;
                }
            }
        }
        // no trailing sync: next iter writes the other parity slot
    }

    // ---- main loop: one sync per output row ----
    for (int i = 0; i < STRIP; ++i) {
        const int y = y0 + i;
        const int s = (i + 1) & 1;   // continues prologue parity (it = 9+i)
        const int rA = y + 5, rS = y - 4;
        const bool vA = ((unsigned)rA < HH), vS = ((unsigned)rS < HH);
        float lA[NC] = {0.f, 0.f, 0.f}, lS[NC] = {0.f, 0.f, 0.f};
        if (vA) { stage(rbA[s], rA); loadL(rA, lA); }
        if (vS) { stage(rbS[s], rS); loadL(rS, lS); }
#pragma unroll
        for (int k = 0; k < DT; ++k) vbuf[s][k][t] = v[k];
        __syncthreads();

        // ---- phase 2: outputs for row y ----
        if (p2 && X < WW) {
            const float4* vb = (const float4*)&vbuf[s][d_k][X - x0];
            float4 w0 = vb[0], w1 = vb[1], w2 = vb[2], w3 = vb[3];
            const float q0 = w0.x, q1 = w0.y, q2 = w0.z, q3 = w0.w;
            const float q4 = w1.x, q5 = w1.y, q6 = w1.z, q7 = w1.w;
            const float q8 = w2.x, q9 = w2.y, q10 = w2.z, q11 = w2.w;
            const float q12 = w3.x, q13 = w3.y, q14 = w3.z, q15 = w3.w;
            float sa[8];
            sa[0] = ((q0 + q1) + (q2 + q3)) + ((q4 + q5) + (q6 + q7)) + q8;
            sa[1] = sa[0] + q9  - q0;
            sa[2] = sa[1] + q10 - q1;
            sa[3] = sa[2] + q11 - q2;
            sa[4] = sa[3] + q12 - q3;
            sa[5] = sa[4] + q13 - q4;
            sa[6] = sa[5] + q14 - q5;
            sa[7] = sa[6] + q15 - q6;

            const int o = y * WW + X;
            float4 lsA = *(const float4*)&LSum[o];
            float4 lsB = *(const float4*)&LSum[o + 4];
            float4 slA = *(const float4*)&sqLa[o];
            float4 slB = *(const float4*)&sqLa[o + 4];
            const float ls[8] = {lsA.x, lsA.y, lsA.z, lsA.w, lsB.x, lsB.y, lsB.z, lsB.w};
            const float sl[8] = {slA.x, slA.y, slA.z, slA.w, slB.x, slB.y, slB.z, slB.w};

            if (X >= d && (X + 7) < (WW - d)) {
                // fast interior path: all 8 cols valid, no zero regions
                float cl[8];
#pragma unroll
                for (int j = 0; j < 8; ++j) {
                    const int od = o + j - d;
                    float num = fmaf(-ls[j], RSn[od], sa[j]) + 1e-6f;
                    float den = fmaf(sl[j], sqRa[od], 1e-6f);
                    cl[j] = num * __builtin_amdgcn_rcpf(den);
                    outRp[od] = cl[j];
                }
                *(float4*)&outLp[o]     = make_float4(cl[0], cl[1], cl[2], cl[3]);
                *(float4*)&outLp[o + 4] = make_float4(cl[4], cl[5], cl[6], cl[7]);
            } else {
#pragma unroll
                for (int j = 0; j < 8; ++j) {
                    const int x = X + j;
                    float cl = 0.f;
                    if (x >= d) {
                        const int od = o + j - d;
                        float num = fmaf(-ls[j], RSn[od], sa[j]) + 1e-6f;
                        float den = fmaf(sl[j], sqRa[od], 1e-6f);
                        cl = num * __builtin_amdgcn_rcpf(den);
                        outRp[od] = cl;
                    }
                    outLp[o + j] = cl;
                    if (x >= WW - d) outRp[o + j] = 0.f;
                }
            }
        }

        // ---- slide vertical sums: rows [y-4,y+4] -> [y-3,y+5] ----
        if (xok) {
#pragma unroll
            for (int k = 0; k < DT; ++k) {
                const int ri = t + 5 - k;
                const bool qv = (xq >= dlo + k);
                float qa = 0.f, qs = 0.f;
                if (vA && qv) {
                    qa = lA[0] * rbA[s][0][ri];
                    qa = fmaf(lA[1], rbA[s][1][ri], qa);
                    qa = fmaf(lA[2], rbA[s][2][ri], qa);
                }
                if (vS && qv) {
                    qs = lS[0] * rbS[s][0][ri];
                    qs = fmaf(lS[1], rbS[s][1][ri], qs);
                    qs = fmaf(lS[2], rbS[s][2][ri], qs);
                }
                v[k] += qa - qs;
            }
        }
        // no trailing sync: next iter writes the other parity slot
    }
}

// ---------------------------------------------------------------------------
extern "C" void kernel_launch(void* const* d_in, const int* in_sizes, int n_in,
                              void* d_out, int out_size, void* d_ws, size_t ws_size,
                              hipStream_t stream) {
    const float* L = (const float*)d_in[0];
    const float* R = (const float*)d_in[1];
    float* out = (float*)d_out;
    float* ws = (float*)d_ws;

    float* hsL  = ws + 0 * (size_t)NP;
    float* hsLL = ws + 1 * (size_t)NP;
    float* hsR  = ws + 2 * (size_t)NP;
    float* hsRR = ws + 3 * (size_t)NP;
    float* LSum = ws + 4 * (size_t)NP;
    float* sqLa = ws + 5 * (size_t)NP;
    float* RSn  = ws + 6 * (size_t)NP;
    float* sqRa = ws + 7 * (size_t)NP;

    dim3 blk(256);
    dim3 g1((WW + 255) / 256, HH);
    k_stats_h<<<g1, blk, 0, stream>>>(L, R, hsL, hsLL, hsR, hsRR);
    k_stats_v<<<g1, blk, 0, stream>>>(hsL, hsLL, hsR, hsRR, LSum, sqLa, RSn, sqRa);

    dim3 g3((WW + OUTC - 1) / OUTC, HH / STRIP, NDT);
    k_cost<<<g3, blk, 0, stream>>>(L, R, LSum, sqLa, RSn, sqRa, out);
}